// Round 6
// baseline (3590.064 us; speedup 1.0000x reference)
//
#include <hip/hip_runtime.h>
#include <hip/hip_bf16.h>
#include <math.h>

// FCTP with all-scalar right operand:
//   o[n,w,m] = alpha * sum_{u,v} x[n,u,m] * z[n,v] * w[u,v,w]
// Fused: t[w,n] = sum_v wb[u][w][v]*z[n,v]   (MFMA, A=w-frag rows=w, B=z-frag cols=node)
//        o[n,w,m] += t[w,n] * x[n,u,m]       (per-lane scalar x from LDS, f16 storage)
// C/D layout: row(w) = q*4+r, col(node) = lane&15  -> epilogue is contiguous 4D-float chunks.
//
// vs round-5 (verified 930us): l0 split into its own kernel with xv batching --
// one ds_read_b128 per node-tile per 8 u's (outer u-loop steps 8, inner fully
// unrolled so all vector indices are static) instead of 4x ds_read_u16 per u.
// Removes the per-iteration lgkmcnt interleave from the MFMA/fold cluster.
// SP 132->136 u16 for 16B-aligned b128 rows (272B stride: 2-way bank alias, free).
// l1/l2 kernels byte-identical to round 5.

typedef __attribute__((ext_vector_type(8))) short short8;
typedef __attribute__((ext_vector_type(4))) float float4v;
typedef __attribute__((ext_vector_type(4))) unsigned short ushort4v;
typedef __attribute__((ext_vector_type(8))) unsigned short ushort8v;

static constexpr int N_FEAT = 480;

__device__ __forceinline__ unsigned short f2bf(float v) {
    __hip_bfloat16 h = __float2bfloat16(v);
    return __builtin_bit_cast(unsigned short, h);
}

__device__ __forceinline__ unsigned short f2h(float v) {
    _Float16 h = (_Float16)v;
    return __builtin_bit_cast(unsigned short, h);
}

__device__ __forceinline__ float h2f(unsigned short b) {
    return (float)__builtin_bit_cast(_Float16, b);
}

// Repack w[u][v(89)][wcol] fp32 -> wb[u][wcol][v(96 pad)] bf16 (v contiguous, 16B-aligned rows)
template<int U>
__global__ void pack_w_kernel(const float* __restrict__ w, unsigned short* __restrict__ wb) {
    const int total = U * U * 96;
    int i = blockIdx.x * 256 + threadIdx.x;
    if (i >= total) return;
    int v = i % 96;
    int uw = i / 96;
    int wcol = uw % U;
    int u = uw / U;
    float val = (v < 89) ? w[(u * 89 + v) * U + wcol] : 0.0f;
    wb[i] = f2bf(val);
}

// ---------------- l0 kernel (D=1, fold-form, batched xv) ----------------
// WG = 64 nodes x 128 w. 4 waves: wn=0 (all nodes), ww = wave (w group of 32).
__global__ __launch_bounds__(256, 3)
void fctp_l0(const float* __restrict__ x, const float* __restrict__ z,
             const unsigned short* __restrict__ wb, float* __restrict__ out,
             int nN, float alpha) {
    constexpr int SP = 136;                    // u16 row stride: 272B, 16B-aligned, 2-way bank
    __shared__ unsigned short xlds[64 * SP];   // x tile in f16

    const int tid  = threadIdx.x;
    const int lane = tid & 63;
    const int ww   = tid >> 6;    // wave -> 32-wide w-col group
    const int q    = lane >> 4;   // quad: k-offset in frags, w-subrow in C
    const int c    = lane & 15;   // w row in A-frag, node col in B-frag/C
    const int nbase = blockIdx.x * 64;

    // ---- stage x tile to LDS as f16 [n_local][col] ----
#pragma unroll
    for (int it = 0; it < 8; ++it) {
        int e  = it * 256 + tid;          // 2048 = 64 nodes * 32 float4-chunks
        int nl = e >> 5;
        int cq = (e & 31) * 4;
        int ng = nbase + nl;
        float4v v = {0.f, 0.f, 0.f, 0.f};
        if (ng < nN)
            v = *reinterpret_cast<const float4v*>(x + ng * N_FEAT + cq);
        ushort4v h;
#pragma unroll
        for (int j = 0; j < 4; ++j)
            h[j] = f2h(v[j]);
        *reinterpret_cast<ushort4v*>(&xlds[nl * SP + cq]) = h;
    }

    // ---- z frags (B operand): lane c -> node, k = q*8+j ----
    short8 zfr[4][3];
#pragma unroll
    for (int nt = 0; nt < 4; ++nt) {
        int ng = nbase + nt * 16 + c;
        if (ng >= nN) ng = nN - 1;         // clamp; stores guarded, fold x=0 for pad rows
        const float* zrow = z + ng * 89;
#pragma unroll
        for (int kk = 0; kk < 3; ++kk) {
            short8 f;
#pragma unroll
            for (int j = 0; j < 8; ++j) {
                int v = kk * 32 + q * 8 + j;
                float val = (v < 89) ? zrow[v] : 0.0f;
                f[j] = (short)f2bf(val);
            }
            zfr[nt][kk] = f;
        }
    }
    __syncthreads();

    // ---- accumulators ----
    float4v oacc[4][2];
#pragma unroll
    for (int nt = 0; nt < 4; ++nt)
#pragma unroll
        for (int wt = 0; wt < 2; ++wt)
            oacc[nt][wt] = float4v{0.f, 0.f, 0.f, 0.f};

    const float4v ZERO4 = {0.f, 0.f, 0.f, 0.f};

    // ---- A(w) frag pointers: lane c -> w row, k = q*8+j ----
    const unsigned short* wptr[2];
#pragma unroll
    for (int wt = 0; wt < 2; ++wt)
        wptr[wt] = wb + (ww * 32 + wt * 16 + c) * 96 + q * 8;

    short8 bfr[2][2][3];
#pragma unroll
    for (int wt = 0; wt < 2; ++wt)
#pragma unroll
        for (int kk = 0; kk < 3; ++kk)
            bfr[0][wt][kk] = *reinterpret_cast<const short8*>(wptr[wt] + kk * 32);

    for (int u0 = 0; u0 < 128; u0 += 8) {
        // one b128 per node-tile covers 8 u's of x (q-quads broadcast, 2-way bank)
        ushort8v xv8[4];
#pragma unroll
        for (int nt = 0; nt < 4; ++nt)
            xv8[nt] = *reinterpret_cast<const ushort8v*>(&xlds[(nt * 16 + c) * SP + u0]);

#pragma unroll
        for (int du = 0; du < 8; ++du) {
            const int u   = u0 + du;
            const int cur = du & 1, nxt = cur ^ 1;
            const int un  = (u + 1 < 128) ? (u + 1) : u;
#pragma unroll
            for (int wt = 0; wt < 2; ++wt)
#pragma unroll
                for (int kk = 0; kk < 3; ++kk)
                    bfr[nxt][wt][kk] = *reinterpret_cast<const short8*>(wptr[wt] + un * (128 * 96) + kk * 32);

            float xv[4];
#pragma unroll
            for (int nt = 0; nt < 4; ++nt)
                xv[nt] = h2f(xv8[nt][du]);         // static index (full unroll)

            __builtin_amdgcn_s_setprio(1);
#pragma unroll
            for (int nt = 0; nt < 4; ++nt)
#pragma unroll
                for (int wt = 0; wt < 2; ++wt) {
                    float4v acc = __builtin_amdgcn_mfma_f32_16x16x32_bf16(bfr[cur][wt][0], zfr[nt][0], ZERO4, 0, 0, 0);
                    acc = __builtin_amdgcn_mfma_f32_16x16x32_bf16(bfr[cur][wt][1], zfr[nt][1], acc, 0, 0, 0);
                    acc = __builtin_amdgcn_mfma_f32_16x16x32_bf16(bfr[cur][wt][2], zfr[nt][2], acc, 0, 0, 0);
#pragma unroll
                    for (int r = 0; r < 4; ++r)
                        oacc[nt][wt][r] += acc[r] * xv[nt];
                }
            __builtin_amdgcn_s_setprio(0);
        }
    }

    // ---- epilogue ----
#pragma unroll
    for (int nt = 0; nt < 4; ++nt) {
        const int node = nbase + nt * 16 + c;
        if (node >= nN) continue;
#pragma unroll
        for (int wt = 0; wt < 2; ++wt) {
            const int w0 = ww * 32 + wt * 16 + q * 4;   // multiple of 4 -> 16B-aligned
            float* o = out + node * N_FEAT + w0;
            *reinterpret_cast<float4v*>(o) =
                float4v{alpha * oacc[nt][wt][0], alpha * oacc[nt][wt][1],
                        alpha * oacc[nt][wt][2], alpha * oacc[nt][wt][3]};
        }
    }
}

// ---------------- l1/l2 kernel (unchanged from round 5, verified) ----------------
template<int U, int D, int NT, int WT, int OFF>
__global__ __launch_bounds__(256, 3)
void fctp_kernel(const float* __restrict__ x, const float* __restrict__ z,
                 const unsigned short* __restrict__ wb, float* __restrict__ out,
                 int nN, float alpha) {
    constexpr int C  = U * D;
    constexpr int SP = C + 4;
    constexpr int GN = 64 / (NT * 16);
    __shared__ unsigned short xlds[64 * SP];

    const int tid  = threadIdx.x;
    const int lane = tid & 63;
    const int wave = tid >> 6;
    const int q    = lane >> 4;
    const int c    = lane & 15;
    const int wn   = wave % GN;
    const int ww   = wave / GN;
    const int nbase = blockIdx.x * 64;

    constexpr int CQ = C / 4;
#pragma unroll
    for (int it = 0; it < C / 16; ++it) {
        int e  = it * 256 + tid;
        int nl = e / CQ;
        int cq = e - nl * CQ;
        int ng = nbase + nl;
        float4v v = {0.f, 0.f, 0.f, 0.f};
        if (ng < nN)
            v = *reinterpret_cast<const float4v*>(x + ng * N_FEAT + OFF + cq * 4);
        ushort4v h;
#pragma unroll
        for (int j = 0; j < 4; ++j)
            h[j] = f2h(v[j]);
        *reinterpret_cast<ushort4v*>(&xlds[nl * SP + cq * 4]) = h;
    }

    short8 zfr[NT][3];
#pragma unroll
    for (int nt = 0; nt < NT; ++nt) {
        int ng = nbase + wn * (NT * 16) + nt * 16 + c;
        if (ng >= nN) ng = nN - 1;
        const float* zrow = z + ng * 89;
#pragma unroll
        for (int kk = 0; kk < 3; ++kk) {
            short8 f;
#pragma unroll
            for (int j = 0; j < 8; ++j) {
                int v = kk * 32 + q * 8 + j;
                float val = (v < 89) ? zrow[v] : 0.0f;
                f[j] = (short)f2bf(val);
            }
            zfr[nt][kk] = f;
        }
    }
    __syncthreads();

    float4v oacc[NT][WT][D];
#pragma unroll
    for (int nt = 0; nt < NT; ++nt)
#pragma unroll
        for (int wt = 0; wt < WT; ++wt)
#pragma unroll
            for (int m = 0; m < D; ++m)
                oacc[nt][wt][m] = float4v{0.f, 0.f, 0.f, 0.f};

    const float4v ZERO4 = {0.f, 0.f, 0.f, 0.f};

    const unsigned short* wptr[WT];
#pragma unroll
    for (int wt = 0; wt < WT; ++wt)
        wptr[wt] = wb + (ww * (WT * 16) + wt * 16 + c) * 96 + q * 8;

    short8 bfr[2][WT][3];
#pragma unroll
    for (int wt = 0; wt < WT; ++wt)
#pragma unroll
        for (int kk = 0; kk < 3; ++kk)
            bfr[0][wt][kk] = *reinterpret_cast<const short8*>(wptr[wt] + kk * 32);

#pragma unroll 2
    for (int u = 0; u < U; ++u) {
        const int cur = u & 1, nxt = cur ^ 1;
        const int un = (u + 1 < U) ? (u + 1) : u;
#pragma unroll
        for (int wt = 0; wt < WT; ++wt)
#pragma unroll
            for (int kk = 0; kk < 3; ++kk)
                bfr[nxt][wt][kk] = *reinterpret_cast<const short8*>(wptr[wt] + un * (U * 96) + kk * 32);

        float xv[NT][D];
#pragma unroll
        for (int nt = 0; nt < NT; ++nt)
#pragma unroll
            for (int m = 0; m < D; ++m)
                xv[nt][m] = h2f(xlds[(wn * (NT * 16) + nt * 16 + c) * SP + u * D + m]);

        __builtin_amdgcn_s_setprio(1);
#pragma unroll
        for (int nt = 0; nt < NT; ++nt)
#pragma unroll
            for (int wt = 0; wt < WT; ++wt) {
                float4v acc = __builtin_amdgcn_mfma_f32_16x16x32_bf16(bfr[cur][wt][0], zfr[nt][0], ZERO4, 0, 0, 0);
                acc = __builtin_amdgcn_mfma_f32_16x16x32_bf16(bfr[cur][wt][1], zfr[nt][1], acc, 0, 0, 0);
                acc = __builtin_amdgcn_mfma_f32_16x16x32_bf16(bfr[cur][wt][2], zfr[nt][2], acc, 0, 0, 0);
#pragma unroll
                for (int m = 0; m < D; ++m)
#pragma unroll
                    for (int r = 0; r < 4; ++r)
                        oacc[nt][wt][m][r] += acc[r] * xv[nt][m];
            }
        __builtin_amdgcn_s_setprio(0);
    }

#pragma unroll
    for (int nt = 0; nt < NT; ++nt) {
        const int node = nbase + wn * (NT * 16) + nt * 16 + c;
        if (node >= nN) continue;
#pragma unroll
        for (int wt = 0; wt < WT; ++wt) {
            const int w0 = ww * (WT * 16) + wt * 16 + q * 4;
            float vals[4 * D];
#pragma unroll
            for (int r = 0; r < 4; ++r)
#pragma unroll
                for (int m = 0; m < D; ++m)
                    vals[r * D + m] = alpha * oacc[nt][wt][m][r];
            float* o = out + node * N_FEAT + OFF + w0 * D;
#pragma unroll
            for (int j = 0; j < D; ++j)
                *reinterpret_cast<float4v*>(o + j * 4) =
                    float4v{vals[j * 4 + 0], vals[j * 4 + 1], vals[j * 4 + 2], vals[j * 4 + 3]};
        }
    }
}

extern "C" void kernel_launch(void* const* d_in, const int* in_sizes, int n_in,
                              void* d_out, int out_size, void* d_ws, size_t ws_size,
                              hipStream_t stream) {
    const float* x  = (const float*)d_in[0];
    const float* z  = (const float*)d_in[1];
    const float* w0 = (const float*)d_in[2];
    const float* w1 = (const float*)d_in[3];
    const float* w2 = (const float*)d_in[4];
    float* out = (float*)d_out;
    const int N = in_sizes[0] / N_FEAT;

    unsigned short* wb0 = (unsigned short*)d_ws;            // 128*128*96 bf16
    unsigned short* wb1 = wb0 + 128 * 128 * 96;             // 64*64*96
    unsigned short* wb2 = wb1 + 64 * 64 * 96;               // 32*32*96

    pack_w_kernel<128><<<(128 * 128 * 96 + 255) / 256, 256, 0, stream>>>(w0, wb0);
    pack_w_kernel<64><<<(64 * 64 * 96 + 255) / 256, 256, 0, stream>>>(w1, wb1);
    pack_w_kernel<32><<<(32 * 32 * 96 + 255) / 256, 256, 0, stream>>>(w2, wb2);

    const int nblocks = (N + 63) / 64;
    const float a0 = 1.0f / sqrtf(128.0f * 89.0f);
    const float a1 = 1.0f / sqrtf(64.0f * 89.0f);
    const float a2 = 1.0f / sqrtf(32.0f * 89.0f);

    // l0: 128x0e — dedicated kernel, batched xv (8 u's per ds_read_b128)
    fctp_l0<<<nblocks, 256, 0, stream>>>(x, z, wb0, out, N, a0);
    // l1: 64x1e  — WG 64n x 64w; waves 32n x 32w (NT=2, WT=2)
    fctp_kernel<64, 3, 2, 2, 128><<<nblocks, 256, 0, stream>>>(x, z, wb1, out, N, a1);
    // l2: 32x2e  — WG 64n x 32w; waves 16n x 32w (NT=1, WT=2)
    fctp_kernel<32, 5, 1, 2, 320><<<nblocks, 256, 0, stream>>>(x, z, wb2, out, N, a2);
}